// Round 3
// baseline (3714.630 us; speedup 1.0000x reference)
//
#include <hip/hip_runtime.h>
#include <math.h>

// Problem constants (from reference)
#define BATCH   4096
#define NPUMP   4
#define NCH     100
#define NTOT    104          // NPUMP + NCH
#define NROWS   128          // padded rows
#define RESPLEN 801
#define NSTEPS  499          // STEPS - 1

// dz = 50000/499
#define DZ_F   100.20040080160321f
#define HDZ_F  50.100200400801604f   // 0.5*dz
#define DZ6_F  16.700066800267202f   // dz/6

typedef float v2f __attribute__((ext_vector_type(2)));

__device__ __forceinline__ float gentry(float fi, float fj, const float* __restrict__ resp_s)
{
    // D[i][j] = f_j - f_i ; ratio[i][j] = f_i / f_j
    float D    = fj - fi;
    float ad   = fabsf(D);
    float fidx = ad / 5.0e10f;          // DF = FS/N_SAMP = 5e10
    int   i0   = (int)fidx;             // floor (fidx >= 0)
    i0 = i0 > (RESPLEN - 2) ? (RESPLEN - 2) : i0;
    float w  = fidx - (float)i0;
    float g  = resp_s[i0] * (1.0f - w) + resp_s[i0 + 1] * w;
    g = (D < 0.0f) ? -g : g;
    float ratio = fi / fj;
    float m  = fmaxf(1.0f, ratio);
    return g * m / 8e-11f;              // / EFFECTIVE_AREA
}

// 256 threads = 4 waves per block, one batch element per block.
// Each ROW of G is split across 2 lanes (lane = row*2 + chunk, chunk in {0,1});
// each lane holds 52 G entries (26 float2) -> ~80 VGPRs total, no spill.
// amdgpu_waves_per_eu(4,4): allocator targets 128 regs, never chases 8-wave/64-reg.
__global__
__attribute__((amdgpu_flat_work_group_size(256, 256)))
__attribute__((amdgpu_waves_per_eu(4, 4)))
void raman_kernel(
    const float* __restrict__ x,        // (BATCH, 8): [wl0..wl3, pw0..pw3]
    const float* __restrict__ resp,     // (801,)
    const float* __restrict__ sigwl,    // (100,)
    float* __restrict__ out)            // (BATCH, 100)
{
    const int b     = blockIdx.x;
    const int tid   = threadIdx.x;      // 0..255
    const int row   = tid >> 1;         // 0..127 (104 real, 24 dummy)
    const int chunk = tid & 1;          // which half of the row

    __shared__ float resp_s[RESPLEN];
    __shared__ __align__(16) float fr_s[NROWS];
    __shared__ __align__(16) float Pb[2][NROWS];

    // stage raman response into LDS
    for (int i = tid; i < RESPLEN; i += 256) resp_s[i] = resp[i];

    const float* xb = x + b * 8;

    // frequencies (one writer per row)
    if (tid < NROWS) {
        float lam;
        if (tid < NPUMP)      lam = xb[tid];
        else if (tid < NTOT)  lam = sigwl[tid - NPUMP];
        else                  lam = 1.0f;           // dummy rows: finite garbage
        fr_s[tid] = 299792458.0f / lam;
    }
    __syncthreads();

    const float loss = 0.0002f * 0.23025850929940458f;   // 2e-4 * ln10/10

    // initial power: pumps |pw|, signals 1e-3, dummy rows 0
    float p;
    if (row < NPUMP)     p = fabsf(xb[NPUMP + row]);
    else if (row < NTOT) p = 0.001f;
    else                 p = 0.0f;

    // ---- build this lane's half-row of G: 26 float2 = 52 VGPRs ----
    v2f G[26];
    {
        const float fi = fr_s[row];
        const v2f* fv = (const v2f*)fr_s + chunk * 26;
        #pragma unroll
        for (int j = 0; j < 26; ++j) {
            v2f fj = fv[j];
            v2f g;
            g.x = gentry(fi, fj.x, resp_s);
            g.y = gentry(fi, fj.y, resp_s);
            G[j] = g;
        }
    }

    // ---- RK4 main loop ----
    auto stage = [&](float ps, int buf) -> float {
        if (chunk == 0) Pb[buf][row] = ps;
        __syncthreads();
        const v2f* pv = (const v2f*)Pb[buf] + chunk * 26;
        v2f a0 = {0.f, 0.f}, a1 = {0.f, 0.f}, a2 = {0.f, 0.f}, a3 = {0.f, 0.f};
        #pragma unroll
        for (int j = 0; j < 24; j += 4) {
            a0 = __builtin_elementwise_fma(G[j + 0], pv[j + 0], a0);
            a1 = __builtin_elementwise_fma(G[j + 1], pv[j + 1], a1);
            a2 = __builtin_elementwise_fma(G[j + 2], pv[j + 2], a2);
            a3 = __builtin_elementwise_fma(G[j + 3], pv[j + 3], a3);
        }
        a0 = __builtin_elementwise_fma(G[24], pv[24], a0);
        a1 = __builtin_elementwise_fma(G[25], pv[25], a1);
        v2f s = (a0 + a1) + (a2 + a3);
        float d = s.x + s.y;
        d += __shfl_xor(d, 1, 64);      // combine the two half-row partials
        return (d - loss) * ps;
    };

    for (int s = 0; s < NSTEPS; ++s) {
        float k1 = stage(p, 0);
        float k2 = stage(fmaf(HDZ_F, k1, p), 1);
        float k3 = stage(fmaf(HDZ_F, k2, p), 0);
        float k4 = stage(fmaf(DZ_F,  k3, p), 1);
        p = fmaf(DZ6_F, (k1 + 2.0f * k2) + (2.0f * k3 + k4), p);
    }

    // ---- output rows NPUMP..NTOT-1 -> (BATCH, 100), one writer per row ----
    if (chunk == 0 && row >= NPUMP && row < NTOT) out[b * NCH + (row - NPUMP)] = p;
}

extern "C" void kernel_launch(void* const* d_in, const int* in_sizes, int n_in,
                              void* d_out, int out_size, void* d_ws, size_t ws_size,
                              hipStream_t stream)
{
    const float* x     = (const float*)d_in[0];
    const float* resp  = (const float*)d_in[1];
    const float* sigwl = (const float*)d_in[2];
    float* out = (float*)d_out;
    raman_kernel<<<BATCH, 256, 0, stream>>>(x, resp, sigwl, out);
}